// Round 14
// baseline (463.258 us; speedup 1.0000x reference)
//
#include <hip/hip_runtime.h>
#include <hip/hip_bf16.h>
#include <hip/hip_fp16.h>

#define BB 4
#define NN 2048
#define DD 128
#define KK 32
#define NPAIR (BB * NN * KK)   // 262144

typedef __attribute__((ext_vector_type(8)))  _Float16 half8;
typedef __attribute__((ext_vector_type(16))) float f32x16;

#define SC_W   256.0f      // weight pre-scale
#define SC_B   4.0f        // activation pre-scale (4: 10x fp16 overflow margin)
#define SC_ACC 1024.0f     // = SC_W * SC_B (bias / init pre-scale)
#define SC_INV 0.0009765625f   // 1/1024

__device__ __forceinline__ float gelu_f(float x) {
    return 0.5f * x * (1.0f + erff(x * 0.70710678118654752440f));
}
__device__ __forceinline__ float softplus_f(float x) {
    return fmaxf(x, 0.0f) + log1pf(expf(-fabsf(x)));
}
// split 8 f32 values (x SC_B) into hi (RNE f16) and lo (RNE f16 residual)
__device__ __forceinline__ void splitpack16(const float* s, int4& hi, int4& lo) {
    unsigned h[8], l[8];
    #pragma unroll
    for (int e = 0; e < 8; ++e) {
        const float sv = s[e] * SC_B;
        const __half hh = __float2half(sv);
        const float res = sv - __half2float(hh);   // exact in f32
        h[e] = (unsigned)__half_as_ushort(hh);
        l[e] = (unsigned)__half_as_ushort(__float2half(res));
    }
    hi.x = (int)((h[1] << 16) | h[0]);
    hi.y = (int)((h[3] << 16) | h[2]);
    hi.z = (int)((h[5] << 16) | h[4]);
    hi.w = (int)((h[7] << 16) | h[6]);
    lo.x = (int)((l[1] << 16) | l[0]);
    lo.y = (int)((l[3] << 16) | l[2]);
    lo.z = (int)((l[5] << 16) | l[4]);
    lo.w = (int)((l[7] << 16) | l[6]);
}
__device__ __forceinline__ f32x16 MFMA(int4 a, int4 b, f32x16 c) {
    return __builtin_amdgcn_mfma_f32_32x32x16_f16(
        __builtin_bit_cast(half8, a), __builtin_bit_cast(half8, b), c, 0, 0, 0);
}

// ---- K0: pack weight A-fragments (transposed convention: A = W^T) ---------
// frag value (set, mt, kk, lane, slot e) = SC_W * W[k = kk*16 + 8*(lane>>5) + e][row = 32*mt + (lane&31)]
__global__ __launch_bounds__(256) void k_prep(
    const float* __restrict__ W1, const float* __restrict__ W2g,
    const float* __restrict__ Wm1, const float* __restrict__ Wa1,
    const float* __restrict__ Wm2, const float* __restrict__ Wa2,
    const float* __restrict__ bm1, const float* __restrict__ ba1,
    const float* __restrict__ b2g,
    int4* __restrict__ gFrag, float* __restrict__ bmba)
{
    const int idx = blockIdx.x * 256 + threadIdx.x;
    if (idx < 192) {
        const float v = idx < 64 ? bm1[idx] : (idx < 128 ? ba1[idx - 64] : b2g[idx - 128]);
        bmba[idx] = v * SC_ACC;
    }
    if (idx >= 72 * 64) return;
    const int lane = idx & 63, fid = idx >> 6;
    const int hh = lane >> 5, cc = lane & 31;
    int hiB, loB, mt, kk, set;
    if (fid < 32)      { set = 0; mt = fid >> 3;        kk = fid & 7;        hiB = 0    + fid * 64;        loB = 2048 + fid * 64; }
    else if (fid < 48) { set = 1; mt = (fid - 32) >> 3; kk = (fid - 32) & 7; hiB = 4096 + (fid - 32) * 64; loB = 5120 + (fid - 32) * 64; }
    else if (fid < 64) { set = 2; mt = (fid - 48) >> 2; kk = (fid - 48) & 3; hiB = 6144 + (fid - 48) * 64; loB = 7168 + (fid - 48) * 64; }
    else               { set = 3; mt = 0;               kk = fid - 64;       hiB = 8192 + (fid - 64) * 64; loB = 8704 + (fid - 64) * 64; }
    const int row = 32 * mt + cc;
    unsigned hi[4], lo[4];
    #pragma unroll
    for (int g = 0; g < 4; ++g) {
        unsigned hs[2], ls[2];
        #pragma unroll
        for (int t = 0; t < 2; ++t) {
            const int k = kk * 16 + 8 * hh + 2 * g + t;
            float vv;
            if (set == 0)      vv = W1[(size_t)(256 + k) * DD + row];
            else if (set == 1) vv = W2g[k * 64 + row];
            else if (set == 2) vv = row < 64 ? Wm1[k * 64 + row] : Wa1[k * 64 + (row - 64)];
            else               vv = (k < 64) ? (row == 0 ? Wm2[k] : 0.0f)
                                             : ((row >= 1 && row < 5) ? Wa2[(k - 64) * 4 + (row - 1)] : 0.0f);
            const float ws = vv * SC_W;
            const __half hf16 = __float2half(ws);
            const float res = ws - __half2float(hf16);
            hs[t] = (unsigned)__half_as_ushort(hf16);
            ls[t] = (unsigned)__half_as_ushort(__float2half(res));
        }
        hi[g] = (hs[1] << 16) | hs[0];
        lo[g] = (ls[1] << 16) | ls[0];
    }
    gFrag[hiB + lane] = make_int4((int)hi[0], (int)hi[1], (int)hi[2], (int)hi[3]);
    gFrag[loB + lane] = make_int4((int)lo[0], (int)lo[1], (int)lo[2], (int)lo[3]);
}

// ---- K1: fold per-node linear parts of layer 1 (outputs pre-scaled) -------
__global__ __launch_bounds__(128) void k_fold(
    const float* __restrict__ h, const float* __restrict__ pos,
    const float* __restrict__ W1, const float* __restrict__ b1,
    float* __restrict__ HA, float* __restrict__ HB)
{
    __shared__ float sh[16][DD];
    const int c = threadIdx.x;
    const int row0 = blockIdx.x * 16;
    for (int r = 0; r < 16; ++r) sh[r][c] = h[(size_t)(row0 + r) * DD + c];
    __syncthreads();
    float accA[16], accB[16];
    #pragma unroll
    for (int r = 0; r < 16; ++r) { accA[r] = 0.f; accB[r] = 0.f; }
    for (int d = 0; d < DD; ++d) {
        const float wa = W1[d * DD + c];
        const float wb = W1[(DD + d) * DD + c];
        #pragma unroll
        for (int r = 0; r < 16; ++r) {
            accA[r] = fmaf(sh[r][d], wa, accA[r]);
            accB[r] = fmaf(sh[r][d], wb, accB[r]);
        }
    }
    const float w0 = W1[(3 * DD + 0) * DD + c];
    const float w1 = W1[(3 * DD + 1) * DD + c];
    const float w2 = W1[(3 * DD + 2) * DD + c];
    const float bb = b1[c];
    for (int r = 0; r < 16; ++r) {
        const int row = row0 + r;
        const int n = row & (NN - 1);
        const float pa = pos[n * 3 + 0] * w0 + pos[n * 3 + 1] * w1 + pos[n * 3 + 2] * w2;
        HA[(size_t)row * DD + c] = (accA[r] + pa + bb) * SC_ACC;
        HB[(size_t)row * DD + c] = (accB[r] - pa) * SC_ACC;
    }
}

// ---- K2: top-32 via bit-pattern bisection threshold + compact + rank ------
// Exact jax tie-break: key = (vbits<<32)|(0xFFFFFFFF-idx) (value desc, idx asc).
__global__ __launch_bounds__(256) void k_topk(
    const float* __restrict__ A, float* __restrict__ topv, int* __restrict__ topi)
{
    __shared__ unsigned long long sKey[4][64];
    const int wid = threadIdx.x >> 6;
    const int lane = threadIdx.x & 63;
    const int row = blockIdx.x * 4 + wid;
    const float4* A4 = (const float4*)(A + (size_t)row * NN);
    float4 v[8];
    #pragma unroll
    for (int rr = 0; rr < 8; ++rr) v[rr] = A4[rr * 64 + lane];

    // bisection on float bit pattern for count(>=t) in [32, 64]
    unsigned tLo = 0u;
    unsigned tHi = 0x3F800000u;
    unsigned t   = 0x3F79FFFFu;
    float tf = __uint_as_float(t);
    for (int iter = 0; iter < 34; ++iter) {
        tf = __uint_as_float(t);
        int c = 0;
        #pragma unroll
        for (int rr = 0; rr < 8; ++rr) {
            c += (v[rr].x >= tf) + (v[rr].y >= tf) + (v[rr].z >= tf) + (v[rr].w >= tf);
        }
        #pragma unroll
        for (int m = 1; m < 64; m <<= 1) c += __shfl_xor(c, m);
        if (c >= 32 && c <= 64) break;
        if (c > 64) tLo = t; else tHi = t;
        if (tHi - tLo <= 1u) break;
        t = (tLo + tHi) >> 1;
    }

    int cl = 0;
    #pragma unroll
    for (int rr = 0; rr < 8; ++rr) {
        cl += (v[rr].x >= tf) + (v[rr].y >= tf) + (v[rr].z >= tf) + (v[rr].w >= tf);
    }
    int pre = cl;
    #pragma unroll
    for (int s = 1; s < 64; s <<= 1) {
        const int o = __shfl_up(pre, s);
        if (lane >= s) pre += o;
    }
    pre -= cl;

    sKey[wid][lane] = 0ULL;
    __syncthreads();
    int off = pre;
    #pragma unroll
    for (int rr = 0; rr < 8; ++rr) {
        const int base = (rr * 64 + lane) * 4;
        const float vals[4] = {v[rr].x, v[rr].y, v[rr].z, v[rr].w};
        #pragma unroll
        for (int q = 0; q < 4; ++q) {
            if (vals[q] >= tf && off < 64) {
                sKey[wid][off] = ((unsigned long long)__float_as_uint(vals[q]) << 32)
                               | (unsigned long long)(0xFFFFFFFFu - (unsigned)(base + q));
                ++off;
            }
        }
    }
    __syncthreads();

    const unsigned long long myK = sKey[wid][lane];
    int rank = 0;
    #pragma unroll 8
    for (int s = 0; s < 64; ++s) rank += (sKey[wid][s] > myK);

    if (rank < KK) {
        topv[(size_t)row * KK + rank] = __uint_as_float((unsigned)(myK >> 32));
        topi[(size_t)row * KK + rank] = (int)(0xFFFFFFFFu - (unsigned)(myK & 0xFFFFFFFFu));
    }
}

// ---- K3: per-pair MLP via split-fp16 MFMA, transposed stages --------------
// Weights read DIRECTLY from global (L2-hot 147 KB table, coalesced b128
// loads) — no LDS at all. LDS=0 lifts the 1-block/CU cap: at 128 VGPR the
// CU fits 2 blocks = 16 waves (was 8), hiding the VALU dependency chains.
// Loaded values are bit-identical to the LDS version — zero numerics risk.
#define SW1H 0
#define SW1L 2048
#define SW2H 4096
#define SW2L 5120
#define SWHH 6144
#define SWHL 7168
#define SWLH 8192
#define SWLL 8704

__global__ __launch_bounds__(512, 2) void k_pairs(
    const float* __restrict__ hptr, const float* __restrict__ HA, const float* __restrict__ HB,
    const int4* __restrict__ gF, const float* __restrict__ bmba,
    const float* __restrict__ bm2g, const float* __restrict__ ba2g,
    const float* __restrict__ mu_scale_p,
    const float* __restrict__ topv, const int* __restrict__ topi,
    float* __restrict__ gated, float* __restrict__ unc_out,
    float* __restrict__ alpha_out)
{
    const int tid = threadIdx.x;
    const int l  = tid & 63;
    const int wid = tid >> 6;
    const int hf = l >> 5;          // lane half
    const int c  = l & 31;          // pair column
    const float sp_scale = softplus_f(mu_scale_p[0]);
    const float bm2v = bm2g[0];
    const float ba20 = ba2g[0], ba21 = ba2g[1], ba22 = ba2g[2], ba23 = ba2g[3];

    for (int tt = 0; tt < 2; ++tt) {
        const int tile = (blockIdx.x * 8 + wid) * 2 + tt;
        const int p = tile * 32 + c;
        const int b = p >> 16;
        const int i = (p & 65535) >> 5;
        const int j = topi[p];
        const float Av = topv[p];
        const size_t ni = (size_t)(b * NN + i) * DD;
        const size_t nj = (size_t)(b * NN + j) * DD;

        // ---- B1: p-vector (h_i .* h_j), split-fp16 fragments --------------
        int4 B1h[8], B1l[8];
        #pragma unroll
        for (int kk = 0; kk < 8; ++kk) {
            const int d0 = kk * 16 + 8 * hf;
            const float4 xi0 = *(const float4*)(hptr + ni + d0);
            const float4 xi1 = *(const float4*)(hptr + ni + d0 + 4);
            const float4 xj0 = *(const float4*)(hptr + nj + d0);
            const float4 xj1 = *(const float4*)(hptr + nj + d0 + 4);
            float s[8];
            s[0] = xi0.x * xj0.x; s[1] = xi0.y * xj0.y;
            s[2] = xi0.z * xj0.z; s[3] = xi0.w * xj0.w;
            s[4] = xi1.x * xj1.x; s[5] = xi1.y * xj1.y;
            s[6] = xi1.z * xj1.z; s[7] = xi1.w * xj1.w;
            splitpack16(s, B1h[kk], B1l[kk]);
        }

        // ---- L1: 128 out-channels (4 mt), init HA_i + HB_j, then GELU -----
        int4 B2h[8], B2l[8];
        #pragma unroll
        for (int mt = 0; mt < 4; ++mt) {
            const int cb = 32 * mt + 4 * hf;
            f32x16 acc;
            {
                const float4 a0 = *(const float4*)(HA + ni + cb);
                const float4 a1 = *(const float4*)(HA + ni + cb + 8);
                const float4 a2 = *(const float4*)(HA + ni + cb + 16);
                const float4 a3 = *(const float4*)(HA + ni + cb + 24);
                const float4 c0 = *(const float4*)(HB + nj + cb);
                const float4 c1 = *(const float4*)(HB + nj + cb + 8);
                const float4 c2 = *(const float4*)(HB + nj + cb + 16);
                const float4 c3 = *(const float4*)(HB + nj + cb + 24);
                acc[0] = a0.x + c0.x; acc[1] = a0.y + c0.y; acc[2] = a0.z + c0.z; acc[3] = a0.w + c0.w;
                acc[4] = a1.x + c1.x; acc[5] = a1.y + c1.y; acc[6] = a1.z + c1.z; acc[7] = a1.w + c1.w;
                acc[8] = a2.x + c2.x; acc[9] = a2.y + c2.y; acc[10] = a2.z + c2.z; acc[11] = a2.w + c2.w;
                acc[12] = a3.x + c3.x; acc[13] = a3.y + c3.y; acc[14] = a3.z + c3.z; acc[15] = a3.w + c3.w;
            }
            #pragma unroll
            for (int kk = 0; kk < 8; ++kk) {
                const int4 aH = gF[SW1H + (mt * 8 + kk) * 64 + l];
                const int4 aL = gF[SW1L + (mt * 8 + kk) * 64 + l];
                acc = MFMA(aH, B1h[kk], acc);
                acc = MFMA(aH, B1l[kk], acc);
                acc = MFMA(aL, B1h[kk], acc);
            }
            float g[16];
            #pragma unroll
            for (int r = 0; r < 16; ++r) g[r] = gelu_f(acc[r] * SC_INV);
            float sA[8], sB[8];
            #pragma unroll
            for (int q = 0; q < 4; ++q) {
                float a0 = g[q], b0 = g[q + 4];
                asm("v_permlane32_swap_b32 %0, %1" : "+v"(a0), "+v"(b0));
                sA[q] = a0; sA[q + 4] = b0;
                float a1 = g[q + 8], b1v = g[q + 12];
                asm("v_permlane32_swap_b32 %0, %1" : "+v"(a1), "+v"(b1v));
                sB[q] = a1; sB[q + 4] = b1v;
            }
            splitpack16(sA, B2h[2 * mt], B2l[2 * mt]);
            splitpack16(sB, B2h[2 * mt + 1], B2l[2 * mt + 1]);
        }

        // ---- L2: pf (64 out-channels, 2 mt), init b2 — NO activation ------
        int4 B3h[4], B3l[4];
        #pragma unroll
        for (int mt = 0; mt < 2; ++mt) {
            const int cb = 32 * mt + 4 * hf;
            const float* bs2 = bmba + 128;
            f32x16 acc;
            {
                const float4 a0 = *(const float4*)(bs2 + cb);
                const float4 a1 = *(const float4*)(bs2 + cb + 8);
                const float4 a2 = *(const float4*)(bs2 + cb + 16);
                const float4 a3 = *(const float4*)(bs2 + cb + 24);
                acc[0] = a0.x; acc[1] = a0.y; acc[2] = a0.z; acc[3] = a0.w;
                acc[4] = a1.x; acc[5] = a1.y; acc[6] = a1.z; acc[7] = a1.w;
                acc[8] = a2.x; acc[9] = a2.y; acc[10] = a2.z; acc[11] = a2.w;
                acc[12] = a3.x; acc[13] = a3.y; acc[14] = a3.z; acc[15] = a3.w;
            }
            #pragma unroll
            for (int kk = 0; kk < 8; ++kk) {
                const int4 aH = gF[SW2H + (mt * 8 + kk) * 64 + l];
                const int4 aL = gF[SW2L + (mt * 8 + kk) * 64 + l];
                acc = MFMA(aH, B2h[kk], acc);
                acc = MFMA(aH, B2l[kk], acc);
                acc = MFMA(aL, B2h[kk], acc);
            }
            float g[16];
            #pragma unroll
            for (int r = 0; r < 16; ++r) g[r] = acc[r] * SC_INV;   // pair_feat: linear
            float sA[8], sB[8];
            #pragma unroll
            for (int q = 0; q < 4; ++q) {
                float a0 = g[q], b0 = g[q + 4];
                asm("v_permlane32_swap_b32 %0, %1" : "+v"(a0), "+v"(b0));
                sA[q] = a0; sA[q + 4] = b0;
                float a1 = g[q + 8], b1v = g[q + 12];
                asm("v_permlane32_swap_b32 %0, %1" : "+v"(a1), "+v"(b1v));
                sB[q] = a1; sB[q + 4] = b1v;
            }
            splitpack16(sA, B3h[2 * mt], B3l[2 * mt]);
            splitpack16(sB, B3h[2 * mt + 1], B3l[2 * mt + 1]);
        }

        // ---- WH: [Wm1 | Wa1] (128 out-channels, 4 mt), init bmba, GELU ----
        int4 B4h[8], B4l[8];
        #pragma unroll
        for (int mt = 0; mt < 4; ++mt) {
            const int cb = 32 * mt + 4 * hf;
            f32x16 acc;
            {
                const float4 a0 = *(const float4*)(bmba + cb);
                const float4 a1 = *(const float4*)(bmba + cb + 8);
                const float4 a2 = *(const float4*)(bmba + cb + 16);
                const float4 a3 = *(const float4*)(bmba + cb + 24);
                acc[0] = a0.x; acc[1] = a0.y; acc[2] = a0.z; acc[3] = a0.w;
                acc[4] = a1.x; acc[5] = a1.y; acc[6] = a1.z; acc[7] = a1.w;
                acc[8] = a2.x; acc[9] = a2.y; acc[10] = a2.z; acc[11] = a2.w;
                acc[12] = a3.x; acc[13] = a3.y; acc[14] = a3.z; acc[15] = a3.w;
            }
            #pragma unroll
            for (int kk = 0; kk < 4; ++kk) {
                const int4 aH = gF[SWHH + (mt * 4 + kk) * 64 + l];
                const int4 aL = gF[SWHL + (mt * 4 + kk) * 64 + l];
                acc = MFMA(aH, B3h[kk], acc);
                acc = MFMA(aH, B3l[kk], acc);
                acc = MFMA(aL, B3h[kk], acc);
            }
            float g[16];
            #pragma unroll
            for (int r = 0; r < 16; ++r) g[r] = gelu_f(acc[r] * SC_INV);
            float sA[8], sB[8];
            #pragma unroll
            for (int q = 0; q < 4; ++q) {
                float a0 = g[q], b0 = g[q + 4];
                asm("v_permlane32_swap_b32 %0, %1" : "+v"(a0), "+v"(b0));
                sA[q] = a0; sA[q + 4] = b0;
                float a1 = g[q + 8], b1v = g[q + 12];
                asm("v_permlane32_swap_b32 %0, %1" : "+v"(a1), "+v"(b1v));
                sB[q] = a1; sB[q + 4] = b1v;
            }
            splitpack16(sA, B4h[2 * mt], B4l[2 * mt]);
            splitpack16(sB, B4h[2 * mt + 1], B4l[2 * mt + 1]);
        }

        // ---- WL: [Wm2 | Wa2 | 0] (rows 0..4 used) -------------------------
        f32x16 acc;
        #pragma unroll
        for (int r = 0; r < 16; ++r) acc[r] = 0.0f;
        #pragma unroll
        for (int kk = 0; kk < 8; ++kk) {
            const int4 aH = gF[SWLH + kk * 64 + l];
            const int4 aL = gF[SWLL + kk * 64 + l];
            acc = MFMA(aH, B4h[kk], acc);
            acc = MFMA(aH, B4l[kk], acc);
            acc = MFMA(aL, B4h[kk], acc);
        }
        // row 4 lives in the other half-wave's acc[0].
        // r4a/r4b start as the same SSA value — force distinct physical regs
        // before the swap (the r4-r6 bug: compiler aliased them -> no-op swap).
        float r4a = acc[0], r4b = acc[0];
        asm volatile("" : "+v"(r4a), "+v"(r4b));   // force distinct physical regs
        asm("v_permlane32_swap_b32 %0, %1" : "+v"(r4a), "+v"(r4b));
        if (l < 32) {
            const float mu_raw = acc[0] * SC_INV + bm2v;
            const float A0 = fminf(fmaxf(softplus_f(acc[1] * SC_INV + ba20) + 1.0f, 1.01f), 1000.0f);
            const float A1 = fminf(fmaxf(softplus_f(acc[2] * SC_INV + ba21) + 1.0f, 1.01f), 1000.0f);
            const float A2 = fminf(fmaxf(softplus_f(acc[3] * SC_INV + ba22) + 1.0f, 1.01f), 1000.0f);
            const float A3 = fminf(fmaxf(softplus_f(r4b    * SC_INV + ba23) + 1.0f, 1.01f), 1000.0f);
            const float S = A0 + A1 + A2 + A3;
            const float u = fminf(4.0f / S, 0.999f);
            const float mu = tanhf(mu_raw) * sp_scale;
            const float gd = (Av + mu) * (1.0f - u);
            gated[p] = gd;
            unc_out[(size_t)(b * NN + i) * NN + j] = u;
            *(float4*)(alpha_out + (size_t)p * 4) = make_float4(A0, A1, A2, A3);
        }
    }
}

// ---- K4a: symmetrize sparse edges + row sums ------------------------------
__global__ __launch_bounds__(256) void k_sym(
    const float* __restrict__ gated, const int* __restrict__ topi,
    float* __restrict__ wsM, int* __restrict__ wsRev, float* __restrict__ rowsum)
{
    const int p = blockIdx.x * 256 + threadIdx.x;
    const int b = p >> 16;
    const int ir = p & 65535;
    const int i = ir >> 5;
    const int j = topi[p];
    const float g = gated[p];
    const int4* jr = (const int4*)(topi + (size_t)(b * NN + j) * KK);
    int rp = -1;
    #pragma unroll
    for (int q = 0; q < 8; ++q) {
        const int4 v = jr[q];
        if (v.x == i) rp = q * 4 + 0;
        if (v.y == i) rp = q * 4 + 1;
        if (v.z == i) rp = q * 4 + 2;
        if (v.w == i) rp = q * 4 + 3;
    }
    const float gT = (rp >= 0) ? gated[(size_t)(b * NN + j) * KK + rp] : 0.0f;
    const float mval = fmaxf(0.5f * (g + gT), 0.0f);
    wsM[p] = mval;
    wsRev[p] = rp;
    float s = mval;
    #pragma unroll
    for (int sh = 1; sh < 32; sh <<= 1) s += __shfl_xor(s, sh);
    if ((threadIdx.x & 31) == 0) atomicAdd(rowsum + (b * NN + i), s);
    if (rp < 0) atomicAdd(rowsum + (b * NN + j), mval);
}

// ---- K4b: normalized sparse writes ----------------------------------------
__global__ __launch_bounds__(256) void k_write(
    const float* __restrict__ wsM, const int* __restrict__ wsRev,
    const int* __restrict__ topi, const float* __restrict__ rowsum,
    float* __restrict__ Aeff)
{
    const int p = blockIdx.x * 256 + threadIdx.x;
    const int b = p >> 16;
    const int ir = p & 65535;
    const int i = ir >> 5;
    const int j = topi[p];
    const float mval = wsM[p];
    const float rsI = fmaxf(rowsum[b * NN + i], 1e-8f);
    Aeff[(size_t)(b * NN + i) * NN + j] = mval / rsI;
    if (wsRev[p] < 0) {
        const float rsJ = fmaxf(rowsum[b * NN + j], 1e-8f);
        Aeff[(size_t)(b * NN + j) * NN + i] = mval / rsJ;
    }
}

extern "C" void kernel_launch(void* const* d_in, const int* in_sizes, int n_in,
                              void* d_out, int out_size, void* d_ws, size_t ws_size,
                              hipStream_t stream)
{
    const float* h    = (const float*)d_in[0];
    const float* pos  = (const float*)d_in[1];
    const float* Ap   = (const float*)d_in[2];
    const float* W1   = (const float*)d_in[3];
    const float* b1   = (const float*)d_in[4];
    const float* W2   = (const float*)d_in[5];
    const float* b2   = (const float*)d_in[6];
    const float* Wm1  = (const float*)d_in[7];
    const float* bm1  = (const float*)d_in[8];
    const float* Wm2  = (const float*)d_in[9];
    const float* bm2  = (const float*)d_in[10];
    const float* Wa1  = (const float*)d_in[11];
    const float* ba1  = (const float*)d_in[12];
    const float* Wa2  = (const float*)d_in[13];
    const float* ba2  = (const float*)d_in[14];
    const float* musc = (const float*)d_in[15];

    const size_t BNN = (size_t)BB * NN * NN;
    float* Aeff  = (float*)d_out;               // outputs are FLOAT32
    float* unc   = Aeff + BNN;
    float* alpha = Aeff + 2 * BNN;

    char* ws = (char*)d_ws;
    float* HA     = (float*)(ws + 0);
    float* HB     = (float*)(ws + 4194304);
    float* topv   = (float*)(ws + 8388608);
    int*   topi   = (int*)  (ws + 9437184);
    float* gated  = (float*)(ws + 10485760);
    float* wsM    = (float*)(ws + 11534336);
    int*   wsRev  = (int*)  (ws + 12582912);
    float* rowsum = (float*)(ws + 13631488);
    int4*  gFrag  = (int4*) (ws + 13664256);
    float* bmba   = (float*)(ws + 13811712);

    hipMemsetAsync(d_out, 0, 2 * BNN * sizeof(float), stream);
    hipMemsetAsync(rowsum, 0, (size_t)BB * NN * sizeof(float), stream);

    k_prep <<<dim3(18), dim3(256), 0, stream>>>(W1, W2, Wm1, Wa1, Wm2, Wa2, bm1, ba1, b2, gFrag, bmba);
    k_fold <<<dim3((BB * NN) / 16), dim3(128), 0, stream>>>(h, pos, W1, b1, HA, HB);
    k_topk <<<dim3((BB * NN) / 4),  dim3(256), 0, stream>>>(Ap, topv, topi);
    k_pairs<<<dim3(512), dim3(512), 0, stream>>>(h, HA, HB, gFrag, bmba,
        bm2, ba2, musc, topv, topi, gated, unc, alpha);
    k_sym  <<<dim3(NPAIR / 256), dim3(256), 0, stream>>>(gated, topi, wsM, wsRev, rowsum);
    k_write<<<dim3(NPAIR / 256), dim3(256), 0, stream>>>(wsM, wsRev, topi, rowsum, Aeff);
}

// Round 15
// 262.429 us; speedup vs baseline: 1.7653x; 1.7653x over previous
//
#include <hip/hip_runtime.h>
#include <hip/hip_bf16.h>
#include <hip/hip_fp16.h>

#define BB 4
#define NN 2048
#define DD 128
#define KK 32
#define NPAIR (BB * NN * KK)   // 262144

typedef __attribute__((ext_vector_type(8)))  _Float16 half8;
typedef __attribute__((ext_vector_type(16))) float f32x16;

#define SC_W   256.0f      // weight pre-scale
#define SC_B   4.0f        // activation pre-scale (4: 10x fp16 overflow margin)
#define SC_ACC 1024.0f     // = SC_W * SC_B (bias / init pre-scale)
#define SC_INV 0.0009765625f   // 1/1024

__device__ __forceinline__ float gelu_f(float x) {
    return 0.5f * x * (1.0f + erff(x * 0.70710678118654752440f));
}
__device__ __forceinline__ float softplus_f(float x) {
    return fmaxf(x, 0.0f) + log1pf(expf(-fabsf(x)));
}
// split 8 f32 values (x SC_B) into hi (RNE f16) and lo (RNE f16 residual)
__device__ __forceinline__ void splitpack16(const float* s, int4& hi, int4& lo) {
    unsigned h[8], l[8];
    #pragma unroll
    for (int e = 0; e < 8; ++e) {
        const float sv = s[e] * SC_B;
        const __half hh = __float2half(sv);
        const float res = sv - __half2float(hh);   // exact in f32
        h[e] = (unsigned)__half_as_ushort(hh);
        l[e] = (unsigned)__half_as_ushort(__float2half(res));
    }
    hi.x = (int)((h[1] << 16) | h[0]);
    hi.y = (int)((h[3] << 16) | h[2]);
    hi.z = (int)((h[5] << 16) | h[4]);
    hi.w = (int)((h[7] << 16) | h[6]);
    lo.x = (int)((l[1] << 16) | l[0]);
    lo.y = (int)((l[3] << 16) | l[2]);
    lo.z = (int)((l[5] << 16) | l[4]);
    lo.w = (int)((l[7] << 16) | l[6]);
}
__device__ __forceinline__ f32x16 MFMA(int4 a, int4 b, f32x16 c) {
    return __builtin_amdgcn_mfma_f32_32x32x16_f16(
        __builtin_bit_cast(half8, a), __builtin_bit_cast(half8, b), c, 0, 0, 0);
}

// ---- K0: pack weight A-fragments (transposed convention: A = W^T) ---------
// frag value (set, mt, kk, lane, slot e) = SC_W * W[k = kk*16 + 8*(lane>>5) + e][row = 32*mt + (lane&31)]
__global__ __launch_bounds__(256) void k_prep(
    const float* __restrict__ W1, const float* __restrict__ W2g,
    const float* __restrict__ Wm1, const float* __restrict__ Wa1,
    const float* __restrict__ Wm2, const float* __restrict__ Wa2,
    const float* __restrict__ bm1, const float* __restrict__ ba1,
    const float* __restrict__ b2g,
    int4* __restrict__ gFrag, float* __restrict__ bmba)
{
    const int idx = blockIdx.x * 256 + threadIdx.x;
    if (idx < 192) {
        const float v = idx < 64 ? bm1[idx] : (idx < 128 ? ba1[idx - 64] : b2g[idx - 128]);
        bmba[idx] = v * SC_ACC;
    }
    if (idx >= 72 * 64) return;
    const int lane = idx & 63, fid = idx >> 6;
    const int hh = lane >> 5, cc = lane & 31;
    int hiB, loB, mt, kk, set;
    if (fid < 32)      { set = 0; mt = fid >> 3;        kk = fid & 7;        hiB = 0    + fid * 64;        loB = 2048 + fid * 64; }
    else if (fid < 48) { set = 1; mt = (fid - 32) >> 3; kk = (fid - 32) & 7; hiB = 4096 + (fid - 32) * 64; loB = 5120 + (fid - 32) * 64; }
    else if (fid < 64) { set = 2; mt = (fid - 48) >> 2; kk = (fid - 48) & 3; hiB = 6144 + (fid - 48) * 64; loB = 7168 + (fid - 48) * 64; }
    else               { set = 3; mt = 0;               kk = fid - 64;       hiB = 8192 + (fid - 64) * 64; loB = 8704 + (fid - 64) * 64; }
    const int row = 32 * mt + cc;
    unsigned hi[4], lo[4];
    #pragma unroll
    for (int g = 0; g < 4; ++g) {
        unsigned hs[2], ls[2];
        #pragma unroll
        for (int t = 0; t < 2; ++t) {
            const int k = kk * 16 + 8 * hh + 2 * g + t;
            float vv;
            if (set == 0)      vv = W1[(size_t)(256 + k) * DD + row];
            else if (set == 1) vv = W2g[k * 64 + row];
            else if (set == 2) vv = row < 64 ? Wm1[k * 64 + row] : Wa1[k * 64 + (row - 64)];
            else               vv = (k < 64) ? (row == 0 ? Wm2[k] : 0.0f)
                                             : ((row >= 1 && row < 5) ? Wa2[(k - 64) * 4 + (row - 1)] : 0.0f);
            const float ws = vv * SC_W;
            const __half hf16 = __float2half(ws);
            const float res = ws - __half2float(hf16);
            hs[t] = (unsigned)__half_as_ushort(hf16);
            ls[t] = (unsigned)__half_as_ushort(__float2half(res));
        }
        hi[g] = (hs[1] << 16) | hs[0];
        lo[g] = (ls[1] << 16) | ls[0];
    }
    gFrag[hiB + lane] = make_int4((int)hi[0], (int)hi[1], (int)hi[2], (int)hi[3]);
    gFrag[loB + lane] = make_int4((int)lo[0], (int)lo[1], (int)lo[2], (int)lo[3]);
}

// ---- K1: fold per-node linear parts of layer 1 (outputs pre-scaled) -------
__global__ __launch_bounds__(128) void k_fold(
    const float* __restrict__ h, const float* __restrict__ pos,
    const float* __restrict__ W1, const float* __restrict__ b1,
    float* __restrict__ HA, float* __restrict__ HB)
{
    __shared__ float sh[16][DD];
    const int c = threadIdx.x;
    const int row0 = blockIdx.x * 16;
    for (int r = 0; r < 16; ++r) sh[r][c] = h[(size_t)(row0 + r) * DD + c];
    __syncthreads();
    float accA[16], accB[16];
    #pragma unroll
    for (int r = 0; r < 16; ++r) { accA[r] = 0.f; accB[r] = 0.f; }
    for (int d = 0; d < DD; ++d) {
        const float wa = W1[d * DD + c];
        const float wb = W1[(DD + d) * DD + c];
        #pragma unroll
        for (int r = 0; r < 16; ++r) {
            accA[r] = fmaf(sh[r][d], wa, accA[r]);
            accB[r] = fmaf(sh[r][d], wb, accB[r]);
        }
    }
    const float w0 = W1[(3 * DD + 0) * DD + c];
    const float w1 = W1[(3 * DD + 1) * DD + c];
    const float w2 = W1[(3 * DD + 2) * DD + c];
    const float bb = b1[c];
    for (int r = 0; r < 16; ++r) {
        const int row = row0 + r;
        const int n = row & (NN - 1);
        const float pa = pos[n * 3 + 0] * w0 + pos[n * 3 + 1] * w1 + pos[n * 3 + 2] * w2;
        HA[(size_t)row * DD + c] = (accA[r] + pa + bb) * SC_ACC;
        HB[(size_t)row * DD + c] = (accB[r] - pa) * SC_ACC;
    }
}

// ---- K2: top-32 via bit-pattern bisection threshold + compact + rank ------
// Exact jax tie-break: key = (vbits<<32)|(0xFFFFFFFF-idx) (value desc, idx asc).
__global__ __launch_bounds__(256) void k_topk(
    const float* __restrict__ A, float* __restrict__ topv, int* __restrict__ topi)
{
    __shared__ unsigned long long sKey[4][64];
    const int wid = threadIdx.x >> 6;
    const int lane = threadIdx.x & 63;
    const int row = blockIdx.x * 4 + wid;
    const float4* A4 = (const float4*)(A + (size_t)row * NN);
    float4 v[8];
    #pragma unroll
    for (int rr = 0; rr < 8; ++rr) v[rr] = A4[rr * 64 + lane];

    // bisection on float bit pattern for count(>=t) in [32, 64]
    unsigned tLo = 0u;
    unsigned tHi = 0x3F800000u;
    unsigned t   = 0x3F79FFFFu;
    float tf = __uint_as_float(t);
    for (int iter = 0; iter < 34; ++iter) {
        tf = __uint_as_float(t);
        int c = 0;
        #pragma unroll
        for (int rr = 0; rr < 8; ++rr) {
            c += (v[rr].x >= tf) + (v[rr].y >= tf) + (v[rr].z >= tf) + (v[rr].w >= tf);
        }
        #pragma unroll
        for (int m = 1; m < 64; m <<= 1) c += __shfl_xor(c, m);
        if (c >= 32 && c <= 64) break;
        if (c > 64) tLo = t; else tHi = t;
        if (tHi - tLo <= 1u) break;
        t = (tLo + tHi) >> 1;
    }

    int cl = 0;
    #pragma unroll
    for (int rr = 0; rr < 8; ++rr) {
        cl += (v[rr].x >= tf) + (v[rr].y >= tf) + (v[rr].z >= tf) + (v[rr].w >= tf);
    }
    int pre = cl;
    #pragma unroll
    for (int s = 1; s < 64; s <<= 1) {
        const int o = __shfl_up(pre, s);
        if (lane >= s) pre += o;
    }
    pre -= cl;

    sKey[wid][lane] = 0ULL;
    __syncthreads();
    int off = pre;
    #pragma unroll
    for (int rr = 0; rr < 8; ++rr) {
        const int base = (rr * 64 + lane) * 4;
        const float vals[4] = {v[rr].x, v[rr].y, v[rr].z, v[rr].w};
        #pragma unroll
        for (int q = 0; q < 4; ++q) {
            if (vals[q] >= tf && off < 64) {
                sKey[wid][off] = ((unsigned long long)__float_as_uint(vals[q]) << 32)
                               | (unsigned long long)(0xFFFFFFFFu - (unsigned)(base + q));
                ++off;
            }
        }
    }
    __syncthreads();

    const unsigned long long myK = sKey[wid][lane];
    int rank = 0;
    #pragma unroll 8
    for (int s = 0; s < 64; ++s) rank += (sKey[wid][s] > myK);

    if (rank < KK) {
        topv[(size_t)row * KK + rank] = __uint_as_float((unsigned)(myK >> 32));
        topi[(size_t)row * KK + rank] = (int)(0xFFFFFFFFu - (unsigned)(myK & 0xFFFFFFFFu));
    }
}

// ---- K3: per-pair MLP via split-fp16 MFMA, transposed stages --------------
// LDS weight staging is load-bearing: the L2-direct variant (r14) spilled
// B-fragments to scratch (+256 MB FETCH and WRITE, 151->345 us). Keep LDS.
#define SW1H 0
#define SW1L 2048
#define SW2H 4096
#define SW2L 5120
#define SWHH 6144
#define SWHL 7168
#define SWLH 8192
#define SWLL 8704

__global__ __launch_bounds__(512, 2) void k_pairs(
    const float* __restrict__ hptr, const float* __restrict__ HA, const float* __restrict__ HB,
    const int4* __restrict__ gFrag, const float* __restrict__ bmba,
    const float* __restrict__ bm2g, const float* __restrict__ ba2g,
    const float* __restrict__ mu_scale_p,
    const float* __restrict__ topv, const int* __restrict__ topi,
    float* __restrict__ gated, float* __restrict__ unc_out,
    float* __restrict__ alpha_out)
{
    __shared__ int4 sF[9216];   // 144 KiB of weight A-fragments
    const int tid = threadIdx.x;
    for (int idx = tid; idx < 9216; idx += 512) sF[idx] = gFrag[idx];
    __syncthreads();

    const int l  = tid & 63;
    const int wid = tid >> 6;
    const int hf = l >> 5;          // lane half
    const int c  = l & 31;          // pair column
    const float sp_scale = softplus_f(mu_scale_p[0]);
    const float bm2v = bm2g[0];
    const float ba20 = ba2g[0], ba21 = ba2g[1], ba22 = ba2g[2], ba23 = ba2g[3];

    for (int tt = 0; tt < 2; ++tt) {
        const int tile = (blockIdx.x * 8 + wid) * 2 + tt;
        const int p = tile * 32 + c;
        const int b = p >> 16;
        const int i = (p & 65535) >> 5;
        const int j = topi[p];
        const float Av = topv[p];
        const size_t ni = (size_t)(b * NN + i) * DD;
        const size_t nj = (size_t)(b * NN + j) * DD;

        // ---- B1: p-vector (h_i .* h_j), split-fp16 fragments --------------
        int4 B1h[8], B1l[8];
        #pragma unroll
        for (int kk = 0; kk < 8; ++kk) {
            const int d0 = kk * 16 + 8 * hf;
            const float4 xi0 = *(const float4*)(hptr + ni + d0);
            const float4 xi1 = *(const float4*)(hptr + ni + d0 + 4);
            const float4 xj0 = *(const float4*)(hptr + nj + d0);
            const float4 xj1 = *(const float4*)(hptr + nj + d0 + 4);
            float s[8];
            s[0] = xi0.x * xj0.x; s[1] = xi0.y * xj0.y;
            s[2] = xi0.z * xj0.z; s[3] = xi0.w * xj0.w;
            s[4] = xi1.x * xj1.x; s[5] = xi1.y * xj1.y;
            s[6] = xi1.z * xj1.z; s[7] = xi1.w * xj1.w;
            splitpack16(s, B1h[kk], B1l[kk]);
        }

        // ---- L1: 128 out-channels (4 mt), init HA_i + HB_j, then GELU -----
        int4 B2h[8], B2l[8];
        #pragma unroll
        for (int mt = 0; mt < 4; ++mt) {
            const int cb = 32 * mt + 4 * hf;
            f32x16 acc;
            {
                const float4 a0 = *(const float4*)(HA + ni + cb);
                const float4 a1 = *(const float4*)(HA + ni + cb + 8);
                const float4 a2 = *(const float4*)(HA + ni + cb + 16);
                const float4 a3 = *(const float4*)(HA + ni + cb + 24);
                const float4 c0 = *(const float4*)(HB + nj + cb);
                const float4 c1 = *(const float4*)(HB + nj + cb + 8);
                const float4 c2 = *(const float4*)(HB + nj + cb + 16);
                const float4 c3 = *(const float4*)(HB + nj + cb + 24);
                acc[0] = a0.x + c0.x; acc[1] = a0.y + c0.y; acc[2] = a0.z + c0.z; acc[3] = a0.w + c0.w;
                acc[4] = a1.x + c1.x; acc[5] = a1.y + c1.y; acc[6] = a1.z + c1.z; acc[7] = a1.w + c1.w;
                acc[8] = a2.x + c2.x; acc[9] = a2.y + c2.y; acc[10] = a2.z + c2.z; acc[11] = a2.w + c2.w;
                acc[12] = a3.x + c3.x; acc[13] = a3.y + c3.y; acc[14] = a3.z + c3.z; acc[15] = a3.w + c3.w;
            }
            #pragma unroll
            for (int kk = 0; kk < 8; ++kk) {
                const int4 aH = sF[SW1H + (mt * 8 + kk) * 64 + l];
                const int4 aL = sF[SW1L + (mt * 8 + kk) * 64 + l];
                acc = MFMA(aH, B1h[kk], acc);
                acc = MFMA(aH, B1l[kk], acc);
                acc = MFMA(aL, B1h[kk], acc);
            }
            float g[16];
            #pragma unroll
            for (int r = 0; r < 16; ++r) g[r] = gelu_f(acc[r] * SC_INV);
            float sA[8], sB[8];
            #pragma unroll
            for (int q = 0; q < 4; ++q) {
                float a0 = g[q], b0 = g[q + 4];
                asm("v_permlane32_swap_b32 %0, %1" : "+v"(a0), "+v"(b0));
                sA[q] = a0; sA[q + 4] = b0;
                float a1 = g[q + 8], b1v = g[q + 12];
                asm("v_permlane32_swap_b32 %0, %1" : "+v"(a1), "+v"(b1v));
                sB[q] = a1; sB[q + 4] = b1v;
            }
            splitpack16(sA, B2h[2 * mt], B2l[2 * mt]);
            splitpack16(sB, B2h[2 * mt + 1], B2l[2 * mt + 1]);
        }

        // ---- L2: pf (64 out-channels, 2 mt), init b2 — NO activation ------
        int4 B3h[4], B3l[4];
        #pragma unroll
        for (int mt = 0; mt < 2; ++mt) {
            const int cb = 32 * mt + 4 * hf;
            const float* bs2 = bmba + 128;
            f32x16 acc;
            {
                const float4 a0 = *(const float4*)(bs2 + cb);
                const float4 a1 = *(const float4*)(bs2 + cb + 8);
                const float4 a2 = *(const float4*)(bs2 + cb + 16);
                const float4 a3 = *(const float4*)(bs2 + cb + 24);
                acc[0] = a0.x; acc[1] = a0.y; acc[2] = a0.z; acc[3] = a0.w;
                acc[4] = a1.x; acc[5] = a1.y; acc[6] = a1.z; acc[7] = a1.w;
                acc[8] = a2.x; acc[9] = a2.y; acc[10] = a2.z; acc[11] = a2.w;
                acc[12] = a3.x; acc[13] = a3.y; acc[14] = a3.z; acc[15] = a3.w;
            }
            #pragma unroll
            for (int kk = 0; kk < 8; ++kk) {
                const int4 aH = sF[SW2H + (mt * 8 + kk) * 64 + l];
                const int4 aL = sF[SW2L + (mt * 8 + kk) * 64 + l];
                acc = MFMA(aH, B2h[kk], acc);
                acc = MFMA(aH, B2l[kk], acc);
                acc = MFMA(aL, B2h[kk], acc);
            }
            float g[16];
            #pragma unroll
            for (int r = 0; r < 16; ++r) g[r] = acc[r] * SC_INV;   // pair_feat: linear
            float sA[8], sB[8];
            #pragma unroll
            for (int q = 0; q < 4; ++q) {
                float a0 = g[q], b0 = g[q + 4];
                asm("v_permlane32_swap_b32 %0, %1" : "+v"(a0), "+v"(b0));
                sA[q] = a0; sA[q + 4] = b0;
                float a1 = g[q + 8], b1v = g[q + 12];
                asm("v_permlane32_swap_b32 %0, %1" : "+v"(a1), "+v"(b1v));
                sB[q] = a1; sB[q + 4] = b1v;
            }
            splitpack16(sA, B3h[2 * mt], B3l[2 * mt]);
            splitpack16(sB, B3h[2 * mt + 1], B3l[2 * mt + 1]);
        }

        // ---- WH: [Wm1 | Wa1] (128 out-channels, 4 mt), init bmba, GELU ----
        int4 B4h[8], B4l[8];
        #pragma unroll
        for (int mt = 0; mt < 4; ++mt) {
            const int cb = 32 * mt + 4 * hf;
            f32x16 acc;
            {
                const float4 a0 = *(const float4*)(bmba + cb);
                const float4 a1 = *(const float4*)(bmba + cb + 8);
                const float4 a2 = *(const float4*)(bmba + cb + 16);
                const float4 a3 = *(const float4*)(bmba + cb + 24);
                acc[0] = a0.x; acc[1] = a0.y; acc[2] = a0.z; acc[3] = a0.w;
                acc[4] = a1.x; acc[5] = a1.y; acc[6] = a1.z; acc[7] = a1.w;
                acc[8] = a2.x; acc[9] = a2.y; acc[10] = a2.z; acc[11] = a2.w;
                acc[12] = a3.x; acc[13] = a3.y; acc[14] = a3.z; acc[15] = a3.w;
            }
            #pragma unroll
            for (int kk = 0; kk < 4; ++kk) {
                const int4 aH = sF[SWHH + (mt * 4 + kk) * 64 + l];
                const int4 aL = sF[SWHL + (mt * 4 + kk) * 64 + l];
                acc = MFMA(aH, B3h[kk], acc);
                acc = MFMA(aH, B3l[kk], acc);
                acc = MFMA(aL, B3h[kk], acc);
            }
            float g[16];
            #pragma unroll
            for (int r = 0; r < 16; ++r) g[r] = gelu_f(acc[r] * SC_INV);
            float sA[8], sB[8];
            #pragma unroll
            for (int q = 0; q < 4; ++q) {
                float a0 = g[q], b0 = g[q + 4];
                asm("v_permlane32_swap_b32 %0, %1" : "+v"(a0), "+v"(b0));
                sA[q] = a0; sA[q + 4] = b0;
                float a1 = g[q + 8], b1v = g[q + 12];
                asm("v_permlane32_swap_b32 %0, %1" : "+v"(a1), "+v"(b1v));
                sB[q] = a1; sB[q + 4] = b1v;
            }
            splitpack16(sA, B4h[2 * mt], B4l[2 * mt]);
            splitpack16(sB, B4h[2 * mt + 1], B4l[2 * mt + 1]);
        }

        // ---- WL: [Wm2 | Wa2 | 0] (rows 0..4 used) -------------------------
        f32x16 acc;
        #pragma unroll
        for (int r = 0; r < 16; ++r) acc[r] = 0.0f;
        #pragma unroll
        for (int kk = 0; kk < 8; ++kk) {
            const int4 aH = sF[SWLH + kk * 64 + l];
            const int4 aL = sF[SWLL + kk * 64 + l];
            acc = MFMA(aH, B4h[kk], acc);
            acc = MFMA(aH, B4l[kk], acc);
            acc = MFMA(aL, B4h[kk], acc);
        }
        // row 4 lives in the other half-wave's acc[0].
        // r4a/r4b start as the same SSA value — force distinct physical regs
        // before the swap (the r4-r6 bug: compiler aliased them -> no-op swap).
        float r4a = acc[0], r4b = acc[0];
        asm volatile("" : "+v"(r4a), "+v"(r4b));   // force distinct physical regs
        asm("v_permlane32_swap_b32 %0, %1" : "+v"(r4a), "+v"(r4b));
        if (l < 32) {
            const float mu_raw = acc[0] * SC_INV + bm2v;
            const float A0 = fminf(fmaxf(softplus_f(acc[1] * SC_INV + ba20) + 1.0f, 1.01f), 1000.0f);
            const float A1 = fminf(fmaxf(softplus_f(acc[2] * SC_INV + ba21) + 1.0f, 1.01f), 1000.0f);
            const float A2 = fminf(fmaxf(softplus_f(acc[3] * SC_INV + ba22) + 1.0f, 1.01f), 1000.0f);
            const float A3 = fminf(fmaxf(softplus_f(r4b    * SC_INV + ba23) + 1.0f, 1.01f), 1000.0f);
            const float S = A0 + A1 + A2 + A3;
            const float u = fminf(4.0f / S, 0.999f);
            const float mu = tanhf(mu_raw) * sp_scale;
            const float gd = (Av + mu) * (1.0f - u);
            gated[p] = gd;
            unc_out[(size_t)(b * NN + i) * NN + j] = u;
            *(float4*)(alpha_out + (size_t)p * 4) = make_float4(A0, A1, A2, A3);
        }
    }
}

// ---- K4a: symmetrize sparse edges + row sums ------------------------------
__global__ __launch_bounds__(256) void k_sym(
    const float* __restrict__ gated, const int* __restrict__ topi,
    float* __restrict__ wsM, int* __restrict__ wsRev, float* __restrict__ rowsum)
{
    const int p = blockIdx.x * 256 + threadIdx.x;
    const int b = p >> 16;
    const int ir = p & 65535;
    const int i = ir >> 5;
    const int j = topi[p];
    const float g = gated[p];
    const int4* jr = (const int4*)(topi + (size_t)(b * NN + j) * KK);
    int rp = -1;
    #pragma unroll
    for (int q = 0; q < 8; ++q) {
        const int4 v = jr[q];
        if (v.x == i) rp = q * 4 + 0;
        if (v.y == i) rp = q * 4 + 1;
        if (v.z == i) rp = q * 4 + 2;
        if (v.w == i) rp = q * 4 + 3;
    }
    const float gT = (rp >= 0) ? gated[(size_t)(b * NN + j) * KK + rp] : 0.0f;
    const float mval = fmaxf(0.5f * (g + gT), 0.0f);
    wsM[p] = mval;
    wsRev[p] = rp;
    float s = mval;
    #pragma unroll
    for (int sh = 1; sh < 32; sh <<= 1) s += __shfl_xor(s, sh);
    if ((threadIdx.x & 31) == 0) atomicAdd(rowsum + (b * NN + i), s);
    if (rp < 0) atomicAdd(rowsum + (b * NN + j), mval);
}

// ---- K4b: normalized sparse writes ----------------------------------------
__global__ __launch_bounds__(256) void k_write(
    const float* __restrict__ wsM, const int* __restrict__ wsRev,
    const int* __restrict__ topi, const float* __restrict__ rowsum,
    float* __restrict__ Aeff)
{
    const int p = blockIdx.x * 256 + threadIdx.x;
    const int b = p >> 16;
    const int ir = p & 65535;
    const int i = ir >> 5;
    const int j = topi[p];
    const float mval = wsM[p];
    const float rsI = fmaxf(rowsum[b * NN + i], 1e-8f);
    Aeff[(size_t)(b * NN + i) * NN + j] = mval / rsI;
    if (wsRev[p] < 0) {
        const float rsJ = fmaxf(rowsum[b * NN + j], 1e-8f);
        Aeff[(size_t)(b * NN + j) * NN + i] = mval / rsJ;
    }
}

extern "C" void kernel_launch(void* const* d_in, const int* in_sizes, int n_in,
                              void* d_out, int out_size, void* d_ws, size_t ws_size,
                              hipStream_t stream)
{
    const float* h    = (const float*)d_in[0];
    const float* pos  = (const float*)d_in[1];
    const float* Ap   = (const float*)d_in[2];
    const float* W1   = (const float*)d_in[3];
    const float* b1   = (const float*)d_in[4];
    const float* W2   = (const float*)d_in[5];
    const float* b2   = (const float*)d_in[6];
    const float* Wm1  = (const float*)d_in[7];
    const float* bm1  = (const float*)d_in[8];
    const float* Wm2  = (const float*)d_in[9];
    const float* bm2  = (const float*)d_in[10];
    const float* Wa1  = (const float*)d_in[11];
    const float* ba1  = (const float*)d_in[12];
    const float* Wa2  = (const float*)d_in[13];
    const float* ba2  = (const float*)d_in[14];
    const float* musc = (const float*)d_in[15];

    const size_t BNN = (size_t)BB * NN * NN;
    float* Aeff  = (float*)d_out;               // outputs are FLOAT32
    float* unc   = Aeff + BNN;
    float* alpha = Aeff + 2 * BNN;

    char* ws = (char*)d_ws;
    float* HA     = (float*)(ws + 0);
    float* HB     = (float*)(ws + 4194304);
    float* topv   = (float*)(ws + 8388608);
    int*   topi   = (int*)  (ws + 9437184);
    float* gated  = (float*)(ws + 10485760);
    float* wsM    = (float*)(ws + 11534336);
    int*   wsRev  = (int*)  (ws + 12582912);
    float* rowsum = (float*)(ws + 13631488);
    int4*  gFrag  = (int4*) (ws + 13664256);
    float* bmba   = (float*)(ws + 13811712);

    hipMemsetAsync(d_out, 0, 2 * BNN * sizeof(float), stream);
    hipMemsetAsync(rowsum, 0, (size_t)BB * NN * sizeof(float), stream);

    k_prep <<<dim3(18), dim3(256), 0, stream>>>(W1, W2, Wm1, Wa1, Wm2, Wa2, bm1, ba1, b2, gFrag, bmba);
    k_fold <<<dim3((BB * NN) / 16), dim3(128), 0, stream>>>(h, pos, W1, b1, HA, HB);
    k_topk <<<dim3((BB * NN) / 4),  dim3(256), 0, stream>>>(Ap, topv, topi);
    k_pairs<<<dim3(512), dim3(512), 0, stream>>>(h, HA, HB, gFrag, bmba,
        bm2, ba2, musc, topv, topi, gated, unc, alpha);
    k_sym  <<<dim3(NPAIR / 256), dim3(256), 0, stream>>>(gated, topi, wsM, wsRev, rowsum);
    k_write<<<dim3(NPAIR / 256), dim3(256), 0, stream>>>(wsM, wsRev, topi, rowsum, Aeff);
}